// Round 1
// baseline (1094.202 us; speedup 1.0000x reference)
//
#include <hip/hip_runtime.h>

// 2-layer GCN: deg/rsqrt -> h=x@W1 -> edge scatter (norm-weighted) -> relu+dot(W2)
// -> scalar edge scatter -> out. Baseline: atomic scatter-add formulation.

__global__ void k_init_deg(float* __restrict__ deg, int n) {
    int i = blockIdx.x * blockDim.x + threadIdx.x;
    if (i < n) deg[i] = 1.0f;  // self-loop contributes 1
}

__global__ void k_count_deg(const int* __restrict__ col, float* __restrict__ deg, int e) {
    int i = blockIdx.x * blockDim.x + threadIdx.x;
    if (i < e) atomicAdd(&deg[col[i]], 1.0f);
}

__global__ void k_rsqrt_inplace(float* __restrict__ d, int n) {
    int i = blockIdx.x * blockDim.x + threadIdx.x;
    if (i < n) d[i] = rsqrtf(d[i]);  // deg >= 1 always (self-loops)
}

// h[N,16] = x[N,128] @ W1[128,16]; W1 staged transposed in LDS (wt[j*128+k]),
// broadcast float4 reads (all lanes same address -> no bank conflict).
__global__ void k_gemm1(const float* __restrict__ x, const float* __restrict__ W1,
                        float* __restrict__ h, int n) {
    __shared__ float wt[16 * 128];
    for (int t = threadIdx.x; t < 2048; t += blockDim.x) {
        int j = t >> 7, k = t & 127;
        wt[t] = W1[k * 16 + j];
    }
    __syncthreads();
    int row = blockIdx.x * blockDim.x + threadIdx.x;
    if (row >= n) return;
    const float4* x4 = (const float4*)(x + (size_t)row * 128);
    const float4* w4 = (const float4*)wt;
    float acc[16];
#pragma unroll
    for (int j = 0; j < 16; ++j) acc[j] = 0.f;
    for (int k4 = 0; k4 < 32; ++k4) {
        float4 v = x4[k4];
#pragma unroll
        for (int j = 0; j < 16; ++j) {
            float4 w = w4[j * 32 + k4];
            acc[j] += v.x * w.x + v.y * w.y + v.z * w.z + v.w * w.w;
        }
    }
    float4* h4 = (float4*)(h + (size_t)row * 16);
    h4[0] = make_float4(acc[0], acc[1], acc[2], acc[3]);
    h4[1] = make_float4(acc[4], acc[5], acc[6], acc[7]);
    h4[2] = make_float4(acc[8], acc[9], acc[10], acc[11]);
    h4[3] = make_float4(acc[12], acc[13], acc[14], acc[15]);
}

// agg[i][:] = dis[i]^2 * h[i][:]   (self-loop term initializes the accumulator)
__global__ void k_self_init1(const float* __restrict__ dis, const float* __restrict__ h,
                             float* __restrict__ agg, int n) {
    int t = blockIdx.x * blockDim.x + threadIdx.x;  // t = i*4 + quarter
    if (t >= n * 4) return;
    int i = t >> 2;
    float d = dis[i];
    float sc = d * d;
    float4 v = ((const float4*)h)[t];
    ((float4*)agg)[t] = make_float4(v.x * sc, v.y * sc, v.z * sc, v.w * sc);
}

// 4 threads per edge, each handles 4 features: agg[col] += dis[r]*dis[c]*h[row]
__global__ void k_scatter1(const int* __restrict__ row, const int* __restrict__ col,
                           const float* __restrict__ dis, const float* __restrict__ h,
                           float* __restrict__ agg, int e) {
    int t = blockIdx.x * blockDim.x + threadIdx.x;
    if (t >= e * 4) return;
    int ei = t >> 2, q = t & 3;
    int r = row[ei], c = col[ei];
    float wgt = dis[r] * dis[c];
    float4 v = ((const float4*)h)[r * 4 + q];
    float* dst = agg + (size_t)c * 16 + q * 4;
    atomicAdd(dst + 0, wgt * v.x);
    atomicAdd(dst + 1, wgt * v.y);
    atomicAdd(dst + 2, wgt * v.z);
    atomicAdd(dst + 3, wgt * v.w);
}

// s[i] = relu(agg[i]+b1) . W2
__global__ void k_relu_dot(const float* __restrict__ agg, const float* __restrict__ b1,
                           const float* __restrict__ W2, float* __restrict__ s, int n) {
    __shared__ float sb[16], sw[16];
    if (threadIdx.x < 16) { sb[threadIdx.x] = b1[threadIdx.x]; sw[threadIdx.x] = W2[threadIdx.x]; }
    __syncthreads();
    int i = blockIdx.x * blockDim.x + threadIdx.x;
    if (i >= n) return;
    float acc = 0.f;
#pragma unroll
    for (int q = 0; q < 4; ++q) {
        float4 v = ((const float4*)agg)[i * 4 + q];
        acc += fmaxf(v.x + sb[q * 4 + 0], 0.f) * sw[q * 4 + 0];
        acc += fmaxf(v.y + sb[q * 4 + 1], 0.f) * sw[q * 4 + 1];
        acc += fmaxf(v.z + sb[q * 4 + 2], 0.f) * sw[q * 4 + 2];
        acc += fmaxf(v.w + sb[q * 4 + 3], 0.f) * sw[q * 4 + 3];
    }
    s[i] = acc;
}

// out[i] = dis[i]^2 * s[i] + b2   (self-loop term + bias; also inits poisoned d_out)
__global__ void k_self_init2(const float* __restrict__ dis, const float* __restrict__ s,
                             const float* __restrict__ b2, float* __restrict__ out, int n) {
    int i = blockIdx.x * blockDim.x + threadIdx.x;
    if (i < n) { float d = dis[i]; out[i] = d * d * s[i] + b2[0]; }
}

__global__ void k_scatter2(const int* __restrict__ row, const int* __restrict__ col,
                           const float* __restrict__ dis, const float* __restrict__ s,
                           float* __restrict__ out, int e) {
    int i = blockIdx.x * blockDim.x + threadIdx.x;
    if (i < e) {
        int r = row[i], c = col[i];
        atomicAdd(&out[c], dis[r] * dis[c] * s[r]);
    }
}

extern "C" void kernel_launch(void* const* d_in, const int* in_sizes, int n_in,
                              void* d_out, int out_size, void* d_ws, size_t ws_size,
                              hipStream_t stream) {
    const float* x  = (const float*)d_in[0];
    const int*   ei = (const int*)d_in[1];
    const float* W1 = (const float*)d_in[2];
    const float* b1 = (const float*)d_in[3];
    const float* W2 = (const float*)d_in[4];
    const float* b2 = (const float*)d_in[5];
    float* out = (float*)d_out;

    const int N = in_sizes[0] / 128;   // 100000
    const int E = in_sizes[1] / 2;     // 3200000
    const int* row = ei;        // edge_index[0] = source j
    const int* col = ei + E;    // edge_index[1] = target i

    // workspace layout (floats): dis[N] | h[16N] | agg[16N] | s[N]  = 13.6 MB
    float* dis = (float*)d_ws;
    float* h   = dis + N;
    float* agg = h + (size_t)N * 16;
    float* s   = agg + (size_t)N * 16;

    auto cdiv = [](int a, int b) { return (a + b - 1) / b; };
    const int T = 256;

    k_init_deg     <<<cdiv(N, T),     T, 0, stream>>>(dis, N);
    k_count_deg    <<<cdiv(E, T),     T, 0, stream>>>(col, dis, E);
    k_rsqrt_inplace<<<cdiv(N, T),     T, 0, stream>>>(dis, N);
    k_gemm1        <<<cdiv(N, T),     T, 0, stream>>>(x, W1, h, N);
    k_self_init1   <<<cdiv(N * 4, T), T, 0, stream>>>(dis, h, agg, N);
    k_scatter1     <<<cdiv(E * 4, T), T, 0, stream>>>(row, col, dis, h, agg, E);
    k_relu_dot     <<<cdiv(N, T),     T, 0, stream>>>(agg, b1, W2, s, N);
    k_self_init2   <<<cdiv(N, T),     T, 0, stream>>>(dis, s, b2, out, N);
    k_scatter2     <<<cdiv(E, T),     T, 0, stream>>>(row, col, dis, s, out, E);
}

// Round 2
// 814.189 us; speedup vs baseline: 1.3439x; 1.3439x over previous
//
#include <hip/hip_runtime.h>

// 2-layer GCN via CSR gather (counting sort by target), no fp32 atomics.
// norm factorization: norm(r,c) = dis[r]*dis[c], so
//   agg1[i][f] = dis[i] * ( sum_e g[src_e][f] + g[i][f] ),  g = dis[row]*(x@W1)
//   out[i]     = dis[i] * ( sum_e t[src_e]    + t[i] ) + b2, t = dis[i]*s[i],
//   s[i] = sum_f relu(agg1[i][f] + b1[f]) * W2[f]

__global__ void k_count(const int* __restrict__ col, int* __restrict__ counts, int e) {
    int i = blockIdx.x * blockDim.x + threadIdx.x;
    if (i < e) atomicAdd(&counts[col[i]], 1);
}

// Single-block chunked exclusive scan of counts -> offsets (and cursor copy).
// Also computes dis[i] = rsqrt(counts[i] + 1) (self-loop degree).
__global__ void k_scan(const int* __restrict__ counts, int* __restrict__ offsets,
                       int* __restrict__ cursor, float* __restrict__ dis, int n) {
    __shared__ int buf[1024];
    __shared__ int carry;
    if (threadIdx.x == 0) carry = 0;
    __syncthreads();
    for (int base = 0; base < n; base += 1024) {
        int i = base + threadIdx.x;
        int v = (i < n) ? counts[i] : 0;
        buf[threadIdx.x] = v;
        __syncthreads();
        // Hillis-Steele inclusive scan
        for (int off = 1; off < 1024; off <<= 1) {
            int t = (threadIdx.x >= off) ? buf[threadIdx.x - off] : 0;
            __syncthreads();
            buf[threadIdx.x] += t;
            __syncthreads();
        }
        int incl = buf[threadIdx.x];
        int excl = incl - v;
        if (i < n) {
            int o = carry + excl;
            offsets[i] = o;
            cursor[i] = o;
            dis[i] = rsqrtf((float)(v + 1));
        }
        __syncthreads();               // all carry reads done
        if (threadIdx.x == 1023) carry += incl;
        __syncthreads();               // carry visible for next chunk
    }
    if (threadIdx.x == 0) offsets[n] = carry;  // == E
}

// counting-sort placement: ssrc holds source node of each edge, grouped by target
__global__ void k_fill(const int* __restrict__ row, const int* __restrict__ col,
                       int* __restrict__ cursor, int* __restrict__ ssrc, int e) {
    int i = blockIdx.x * blockDim.x + threadIdx.x;
    if (i < e) {
        int c = col[i];
        int p = atomicAdd(&cursor[c], 1);
        ssrc[p] = row[i];
    }
}

// g[N,16] = dis[row] * (x[N,128] @ W1[128,16]); W1 transposed in LDS, broadcast reads
__global__ void k_gemm1(const float* __restrict__ x, const float* __restrict__ W1,
                        const float* __restrict__ dis, float* __restrict__ g, int n) {
    __shared__ float wt[16 * 128];
    for (int t = threadIdx.x; t < 2048; t += blockDim.x) {
        int j = t >> 7, k = t & 127;
        wt[t] = W1[k * 16 + j];
    }
    __syncthreads();
    int r = blockIdx.x * blockDim.x + threadIdx.x;
    if (r >= n) return;
    const float4* x4 = (const float4*)(x + (size_t)r * 128);
    const float4* w4 = (const float4*)wt;
    float acc[16];
#pragma unroll
    for (int j = 0; j < 16; ++j) acc[j] = 0.f;
    for (int k4 = 0; k4 < 32; ++k4) {
        float4 v = x4[k4];
#pragma unroll
        for (int j = 0; j < 16; ++j) {
            float4 w = w4[j * 32 + k4];
            acc[j] += v.x * w.x + v.y * w.y + v.z * w.z + v.w * w.w;
        }
    }
    float d = dis[r];
    float4* g4 = (float4*)(g + (size_t)r * 16);
    g4[0] = make_float4(d * acc[0], d * acc[1], d * acc[2], d * acc[3]);
    g4[1] = make_float4(d * acc[4], d * acc[5], d * acc[6], d * acc[7]);
    g4[2] = make_float4(d * acc[8], d * acc[9], d * acc[10], d * acc[11]);
    g4[3] = make_float4(d * acc[12], d * acc[13], d * acc[14], d * acc[15]);
}

// 16 threads per node (one per feature); fused gather + relu + bias + dot(W2).
// t[i] = dis[i] * sum_f relu(dis[i]*(sum_e g[src][f] + g[i][f]) + b1[f]) * W2[f]
__global__ void k_gather1(const int* __restrict__ offsets, const int* __restrict__ ssrc,
                          const float* __restrict__ g, const float* __restrict__ dis,
                          const float* __restrict__ b1, const float* __restrict__ W2,
                          float* __restrict__ tbuf, int n) {
    int t = blockIdx.x * blockDim.x + threadIdx.x;
    if (t >= n * 16) return;
    int i = t >> 4, f = t & 15;
    float di = dis[i];
    int beg = offsets[i], end = offsets[i + 1];
    float acc = g[(size_t)i * 16 + f];           // self-loop term
    for (int e = beg; e < end; ++e)
        acc += g[(size_t)ssrc[e] * 16 + f];      // 16 lanes read 64 contiguous bytes
    float u = fmaxf(di * acc + b1[f], 0.f) * W2[f];
#pragma unroll
    for (int m = 8; m >= 1; m >>= 1) u += __shfl_xor(u, m, 16);
    if (f == 0) tbuf[i] = di * u;
}

// out[i] = dis[i] * (sum_e t[src] + t[i]) + b2
__global__ void k_gather2(const int* __restrict__ offsets, const int* __restrict__ ssrc,
                          const float* __restrict__ tbuf, const float* __restrict__ dis,
                          const float* __restrict__ b2, float* __restrict__ out, int n) {
    int i = blockIdx.x * blockDim.x + threadIdx.x;
    if (i >= n) return;
    float acc = tbuf[i];
    int beg = offsets[i], end = offsets[i + 1];
    for (int e = beg; e < end; ++e) acc += tbuf[ssrc[e]];
    out[i] = dis[i] * acc + b2[0];
}

extern "C" void kernel_launch(void* const* d_in, const int* in_sizes, int n_in,
                              void* d_out, int out_size, void* d_ws, size_t ws_size,
                              hipStream_t stream) {
    const float* x  = (const float*)d_in[0];
    const int*   ei = (const int*)d_in[1];
    const float* W1 = (const float*)d_in[2];
    const float* b1 = (const float*)d_in[3];
    const float* W2 = (const float*)d_in[4];
    const float* b2 = (const float*)d_in[5];
    float* out = (float*)d_out;

    const int N = in_sizes[0] / 128;   // 100000
    const int E = in_sizes[1] / 2;     // 3200000
    const int* row = ei;        // edge_index[0] = source
    const int* col = ei + E;    // edge_index[1] = target

    // workspace (4B units): dis[N] | g[16N] | tbuf[N] | counts[N] | offsets[N+1] | cursor[N] | ssrc[E]
    float* dis    = (float*)d_ws;
    float* g      = dis + N;
    float* tbuf   = g + (size_t)N * 16;
    int* counts   = (int*)(tbuf + N);
    int* offsets  = counts + N;
    int* cursor   = offsets + (N + 1);
    int* ssrc     = cursor + N;

    auto cdiv = [](int a, int b) { return (a + b - 1) / b; };
    const int T = 256;

    hipMemsetAsync(counts, 0, (size_t)N * sizeof(int), stream);
    k_count  <<<cdiv(E, T),      T,    0, stream>>>(col, counts, E);
    k_scan   <<<1,               1024, 0, stream>>>(counts, offsets, cursor, dis, N);
    k_fill   <<<cdiv(E, T),      T,    0, stream>>>(row, col, cursor, ssrc, E);
    k_gemm1  <<<cdiv(N, T),      T,    0, stream>>>(x, W1, dis, g, N);
    k_gather1<<<cdiv(N * 16, T), T,    0, stream>>>(offsets, ssrc, g, dis, b1, W2, tbuf, N);
    k_gather2<<<cdiv(N, T),      T,    0, stream>>>(offsets, ssrc, tbuf, dis, b2, out, N);
}

// Round 3
// 341.961 us; speedup vs baseline: 3.1998x; 2.3809x over previous
//
#include <hip/hip_runtime.h>

// 2-layer GCN via CSR gather built by a two-level counting sort.
// Level 1: partition edges into 256-node coarse buckets (block-owned write runs).
// Level 2: one block per bucket does the fine counting sort entirely in LDS,
//          emitting offsets[], dis[] and ssrc[] with no global fine atomics.
// Then: g = dis*(x@W1); gather+relu+dot(W2) -> t; gather t -> out.

#define CB 8                 // coarse bucket = col >> CB (256 nodes/bucket)
#define TILE 4096            // edges per partition block (256 thr x 16)

__global__ void k_coarse_count(const int* __restrict__ col, int* __restrict__ cc,
                               int e, int nb) {
    __shared__ int hist[512];
    for (int t = threadIdx.x; t < nb; t += blockDim.x) hist[t] = 0;
    __syncthreads();
    int stride = gridDim.x * blockDim.x;
    for (int i = blockIdx.x * blockDim.x + threadIdx.x; i < e; i += stride)
        atomicAdd(&hist[col[i] >> CB], 1);
    __syncthreads();
    for (int t = threadIdx.x; t < nb; t += blockDim.x)
        if (hist[t]) atomicAdd(&cc[t], hist[t]);
}

__global__ void k_coarse_scan(const int* __restrict__ cc, int* __restrict__ coff,
                              int* __restrict__ gcur, int nb) {
    __shared__ int sc[512];
    int t = threadIdx.x;
    int v = (t < nb) ? cc[t] : 0;
    sc[t] = v;
    __syncthreads();
    for (int off = 1; off < 512; off <<= 1) {
        int add = (t >= off) ? sc[t - off] : 0;
        __syncthreads();
        sc[t] += add;
        __syncthreads();
    }
    int excl = sc[t] - v;
    if (t < nb) { coff[t] = excl; gcur[t] = excl; }
    if (t == nb - 1) coff[nb] = sc[t];
}

// Pack (col&255)<<17 | row  (row < 2^17). Per-block LDS ranking so each bucket's
// global run is written by a single block (single CU -> L2 write-back once).
__global__ void __launch_bounds__(256) k_partition(
        const int* __restrict__ row, const int* __restrict__ col,
        int* __restrict__ gcur, int* __restrict__ ebuf, int e, int nb) {
    __shared__ int hist[512];
    __shared__ int gbase[512];
    const int base = blockIdx.x * TILE;
    for (int t = threadIdx.x; t < nb; t += 256) hist[t] = 0;
    __syncthreads();
    int myb[16], myv[16];
#pragma unroll
    for (int k = 0; k < 16; ++k) {
        int i = base + (k << 8) + threadIdx.x;
        if (i < e) {
            int c = col[i], r = row[i];
            int b = c >> CB;
            myb[k] = b;
            myv[k] = ((c & ((1 << CB) - 1)) << 17) | r;
            atomicAdd(&hist[b], 1);
        } else myb[k] = -1;
    }
    __syncthreads();
    for (int t = threadIdx.x; t < nb; t += 256) {
        int h = hist[t];
        gbase[t] = h ? atomicAdd(&gcur[t], h) : 0;
        hist[t] = 0;  // reuse as local cursor
    }
    __syncthreads();
#pragma unroll
    for (int k = 0; k < 16; ++k) {
        if (myb[k] >= 0) {
            int p = gbase[myb[k]] + atomicAdd(&hist[myb[k]], 1);
            ebuf[p] = myv[k];
        }
    }
}

// One block per bucket: fine histogram + scan in LDS -> offsets, dis, ssrc.
__global__ void __launch_bounds__(256) k_bucket(
        const int* __restrict__ ebuf, const int* __restrict__ coff,
        int* __restrict__ offsets, int* __restrict__ ssrc,
        float* __restrict__ dis, int n, int e) {
    __shared__ int hist[256];
    __shared__ int sc[256];
    const int b = blockIdx.x, t = threadIdx.x;
    const int nstart = b << CB;
    const int cbeg = coff[b], cend = coff[b + 1];
    hist[t] = 0;
    __syncthreads();
    for (int i = cbeg + t; i < cend; i += 256) atomicAdd(&hist[ebuf[i] >> 17], 1);
    __syncthreads();
    int v = hist[t];
    sc[t] = v;
    __syncthreads();
    for (int off = 1; off < 256; off <<= 1) {
        int add = (t >= off) ? sc[t - off] : 0;
        __syncthreads();
        sc[t] += add;
        __syncthreads();
    }
    int excl = sc[t] - v;
    int node = nstart + t;
    if (node < n) {
        offsets[node] = cbeg + excl;
        dis[node] = rsqrtf((float)(v + 1));
    }
    if (b == 0 && t == 0) offsets[n] = e;
    hist[t] = excl;  // local cursor
    __syncthreads();
    for (int i = cbeg + t; i < cend; i += 256) {
        int val = ebuf[i];
        int p = atomicAdd(&hist[val >> 17], 1);
        ssrc[cbeg + p] = val & 0x1FFFF;
    }
}

// g[N,16] = dis[row] * (x[N,128] @ W1[128,16]); W1 transposed in LDS
__global__ void k_gemm1(const float* __restrict__ x, const float* __restrict__ W1,
                        const float* __restrict__ dis, float* __restrict__ g, int n) {
    __shared__ float wt[16 * 128];
    for (int t = threadIdx.x; t < 2048; t += blockDim.x) {
        int j = t >> 7, k = t & 127;
        wt[t] = W1[k * 16 + j];
    }
    __syncthreads();
    int r = blockIdx.x * blockDim.x + threadIdx.x;
    if (r >= n) return;
    const float4* x4 = (const float4*)(x + (size_t)r * 128);
    const float4* w4 = (const float4*)wt;
    float acc[16];
#pragma unroll
    for (int j = 0; j < 16; ++j) acc[j] = 0.f;
    for (int k4 = 0; k4 < 32; ++k4) {
        float4 vv = x4[k4];
#pragma unroll
        for (int j = 0; j < 16; ++j) {
            float4 w = w4[j * 32 + k4];
            acc[j] += vv.x * w.x + vv.y * w.y + vv.z * w.z + vv.w * w.w;
        }
    }
    float d = dis[r];
    float4* g4 = (float4*)(g + (size_t)r * 16);
    g4[0] = make_float4(d * acc[0], d * acc[1], d * acc[2], d * acc[3]);
    g4[1] = make_float4(d * acc[4], d * acc[5], d * acc[6], d * acc[7]);
    g4[2] = make_float4(d * acc[8], d * acc[9], d * acc[10], d * acc[11]);
    g4[3] = make_float4(d * acc[12], d * acc[13], d * acc[14], d * acc[15]);
}

// 16 threads/node: fused gather + relu + bias + dot(W2) -> t[i] = dis[i]*s[i]
__global__ void k_gather1(const int* __restrict__ offsets, const int* __restrict__ ssrc,
                          const float* __restrict__ g, const float* __restrict__ dis,
                          const float* __restrict__ b1, const float* __restrict__ W2,
                          float* __restrict__ tbuf, int n) {
    int t = blockIdx.x * blockDim.x + threadIdx.x;
    if (t >= n * 16) return;
    int i = t >> 4, f = t & 15;
    float di = dis[i];
    int beg = offsets[i], end = offsets[i + 1];
    float acc = g[(size_t)i * 16 + f];  // self-loop
    for (int e = beg; e < end; ++e)
        acc += g[(size_t)ssrc[e] * 16 + f];
    float u = fmaxf(di * acc + b1[f], 0.f) * W2[f];
#pragma unroll
    for (int m = 8; m >= 1; m >>= 1) u += __shfl_xor(u, m, 16);
    if (f == 0) tbuf[i] = di * u;
}

// out[i] = dis[i] * (sum_e t[src] + t[i]) + b2
__global__ void k_gather2(const int* __restrict__ offsets, const int* __restrict__ ssrc,
                          const float* __restrict__ tbuf, const float* __restrict__ dis,
                          const float* __restrict__ b2, float* __restrict__ out, int n) {
    int i = blockIdx.x * blockDim.x + threadIdx.x;
    if (i >= n) return;
    float acc = tbuf[i];
    int beg = offsets[i], end = offsets[i + 1];
    for (int e = beg; e < end; ++e) acc += tbuf[ssrc[e]];
    out[i] = dis[i] * acc + b2[0];
}

extern "C" void kernel_launch(void* const* d_in, const int* in_sizes, int n_in,
                              void* d_out, int out_size, void* d_ws, size_t ws_size,
                              hipStream_t stream) {
    const float* x  = (const float*)d_in[0];
    const int*   ei = (const int*)d_in[1];
    const float* W1 = (const float*)d_in[2];
    const float* b1 = (const float*)d_in[3];
    const float* W2 = (const float*)d_in[4];
    const float* b2 = (const float*)d_in[5];
    float* out = (float*)d_out;

    const int N = in_sizes[0] / 128;   // 100000
    const int E = in_sizes[1] / 2;     // 3200000
    const int* row = ei;        // edge_index[0] = source
    const int* col = ei + E;    // edge_index[1] = target
    const int NB = (N + 255) >> CB;    // coarse buckets (391)

    // workspace (4B units), big region first for float4 alignment of g:
    // big[max(E,16N)] (ebuf, later aliased by g) | dis[N] | tbuf[N] | offsets[N+1]
    // | ssrc[E] | cc[512] | coff[513] | gcur[512]
    size_t bigsz = (size_t)E > (size_t)N * 16 ? (size_t)E : (size_t)N * 16;
    int*   ebuf    = (int*)d_ws;
    float* g       = (float*)d_ws;      // aliases ebuf (ebuf dead before gemm1)
    float* dis     = (float*)d_ws + bigsz;
    float* tbuf    = dis + N;
    int*   offsets = (int*)(tbuf + N);
    int*   ssrc    = offsets + (N + 1);
    int*   cc      = ssrc + E;
    int*   coff    = cc + 512;
    int*   gcur    = coff + 513;

    auto cdiv = [](int a, int b) { return (a + b - 1) / b; };

    hipMemsetAsync(cc, 0, 512 * sizeof(int), stream);
    k_coarse_count<<<512,             256, 0, stream>>>(col, cc, E, NB);
    k_coarse_scan <<<1,               512, 0, stream>>>(cc, coff, gcur, NB);
    k_partition   <<<cdiv(E, TILE),   256, 0, stream>>>(row, col, gcur, ebuf, E, NB);
    k_bucket      <<<NB,              256, 0, stream>>>(ebuf, coff, offsets, ssrc, dis, N, E);
    k_gemm1       <<<cdiv(N, 256),    256, 0, stream>>>(x, W1, dis, g, N);
    k_gather1     <<<cdiv(N * 16, 256), 256, 0, stream>>>(offsets, ssrc, g, dis, b1, W2, tbuf, N);
    k_gather2     <<<cdiv(N, 256),    256, 0, stream>>>(offsets, ssrc, tbuf, dis, b2, out, N);
}

// Round 4
// 287.115 us; speedup vs baseline: 3.8110x; 1.1910x over previous
//
#include <hip/hip_runtime.h>
#include <hip/hip_fp16.h>

// 2-layer GCN via CSR gather built by a two-level counting sort.
// Level 1: partition edges into 256-node coarse buckets (block-owned write runs).
// Level 2: one block per bucket does the fine counting sort entirely in LDS.
// Then: g = fp16(dis*(x@W1)) [3.2MB table, fits per-XCD L2];
//       gather1 (8 lanes/node, half2) + relu + dot(W2) -> t; gather2 t -> out.

#define CB 8                 // coarse bucket = col >> CB (256 nodes/bucket)
#define TILE 4096            // edges per partition block (256 thr x 16)

__global__ void k_coarse_count(const int* __restrict__ col, int* __restrict__ cc,
                               int e, int nb) {
    __shared__ int hist[512];
    for (int t = threadIdx.x; t < nb; t += blockDim.x) hist[t] = 0;
    __syncthreads();
    int stride = gridDim.x * blockDim.x;
    for (int i = blockIdx.x * blockDim.x + threadIdx.x; i < e; i += stride)
        atomicAdd(&hist[col[i] >> CB], 1);
    __syncthreads();
    for (int t = threadIdx.x; t < nb; t += blockDim.x)
        if (hist[t]) atomicAdd(&cc[t], hist[t]);
}

__global__ void k_coarse_scan(const int* __restrict__ cc, int* __restrict__ coff,
                              int* __restrict__ gcur, int nb) {
    __shared__ int sc[512];
    int t = threadIdx.x;
    int v = (t < nb) ? cc[t] : 0;
    sc[t] = v;
    __syncthreads();
    for (int off = 1; off < 512; off <<= 1) {
        int add = (t >= off) ? sc[t - off] : 0;
        __syncthreads();
        sc[t] += add;
        __syncthreads();
    }
    int excl = sc[t] - v;
    if (t < nb) { coff[t] = excl; gcur[t] = excl; }
    if (t == nb - 1) coff[nb] = sc[t];
}

// Pack (col&255)<<17 | row  (row < 2^17). Per-block LDS ranking so each bucket's
// global run is written by a single block.
__global__ void __launch_bounds__(256) k_partition(
        const int* __restrict__ row, const int* __restrict__ col,
        int* __restrict__ gcur, int* __restrict__ ebuf, int e, int nb) {
    __shared__ int hist[512];
    __shared__ int gbase[512];
    const int base = blockIdx.x * TILE;
    for (int t = threadIdx.x; t < nb; t += 256) hist[t] = 0;
    __syncthreads();
    int myb[16], myv[16];
#pragma unroll
    for (int k = 0; k < 16; ++k) {
        int i = base + (k << 8) + threadIdx.x;
        if (i < e) {
            int c = col[i], r = row[i];
            int b = c >> CB;
            myb[k] = b;
            myv[k] = ((c & ((1 << CB) - 1)) << 17) | r;
            atomicAdd(&hist[b], 1);
        } else myb[k] = -1;
    }
    __syncthreads();
    for (int t = threadIdx.x; t < nb; t += 256) {
        int h = hist[t];
        gbase[t] = h ? atomicAdd(&gcur[t], h) : 0;
        hist[t] = 0;  // reuse as local cursor
    }
    __syncthreads();
#pragma unroll
    for (int k = 0; k < 16; ++k) {
        if (myb[k] >= 0) {
            int p = gbase[myb[k]] + atomicAdd(&hist[myb[k]], 1);
            ebuf[p] = myv[k];
        }
    }
}

// One block per bucket: fine histogram + scan in LDS -> offsets, dis, ssrc.
__global__ void __launch_bounds__(256) k_bucket(
        const int* __restrict__ ebuf, const int* __restrict__ coff,
        int* __restrict__ offsets, int* __restrict__ ssrc,
        float* __restrict__ dis, int n, int e) {
    __shared__ int hist[256];
    __shared__ int sc[256];
    const int b = blockIdx.x, t = threadIdx.x;
    const int nstart = b << CB;
    const int cbeg = coff[b], cend = coff[b + 1];
    hist[t] = 0;
    __syncthreads();
    for (int i = cbeg + t; i < cend; i += 256) atomicAdd(&hist[ebuf[i] >> 17], 1);
    __syncthreads();
    int v = hist[t];
    sc[t] = v;
    __syncthreads();
    for (int off = 1; off < 256; off <<= 1) {
        int add = (t >= off) ? sc[t - off] : 0;
        __syncthreads();
        sc[t] += add;
        __syncthreads();
    }
    int excl = sc[t] - v;
    int node = nstart + t;
    if (node < n) {
        offsets[node] = cbeg + excl;
        dis[node] = rsqrtf((float)(v + 1));
    }
    if (b == 0 && t == 0) offsets[n] = e;
    hist[t] = excl;  // local cursor
    __syncthreads();
    for (int i = cbeg + t; i < cend; i += 256) {
        int val = ebuf[i];
        int p = atomicAdd(&hist[val >> 17], 1);
        ssrc[cbeg + p] = val & 0x1FFFF;
    }
}

// g[N,16] (fp16) = dis[row] * (x[N,128] @ W1[128,16]); W1 transposed in LDS
__global__ void k_gemm1(const float* __restrict__ x, const float* __restrict__ W1,
                        const float* __restrict__ dis, __half* __restrict__ gh, int n) {
    __shared__ float wt[16 * 128];
    for (int t = threadIdx.x; t < 2048; t += blockDim.x) {
        int j = t >> 7, k = t & 127;
        wt[t] = W1[k * 16 + j];
    }
    __syncthreads();
    int r = blockIdx.x * blockDim.x + threadIdx.x;
    if (r >= n) return;
    const float4* x4 = (const float4*)(x + (size_t)r * 128);
    const float4* w4 = (const float4*)wt;
    float acc[16];
#pragma unroll
    for (int j = 0; j < 16; ++j) acc[j] = 0.f;
    for (int k4 = 0; k4 < 32; ++k4) {
        float4 vv = x4[k4];
#pragma unroll
        for (int j = 0; j < 16; ++j) {
            float4 w = w4[j * 32 + k4];
            acc[j] += vv.x * w.x + vv.y * w.y + vv.z * w.z + vv.w * w.w;
        }
    }
    float d = dis[r];
    __half2 hh[8];
#pragma unroll
    for (int j = 0; j < 8; ++j)
        hh[j] = __floats2half2_rn(d * acc[2 * j], d * acc[2 * j + 1]);
    uint4* o = (uint4*)(gh + (size_t)r * 16);
    const uint4* src = (const uint4*)hh;
    o[0] = src[0];
    o[1] = src[1];
}

// 8 threads/node, half2 reads (32B/edge, L2-resident table); fp32 accumulate;
// fused relu + bias + dot(W2): t[i] = dis[i]*s[i]
__global__ void k_gather1(const int* __restrict__ offsets, const int* __restrict__ ssrc,
                          const __half2* __restrict__ g2, const float* __restrict__ dis,
                          const float* __restrict__ b1, const float* __restrict__ W2,
                          float* __restrict__ tbuf, int n) {
    int t = blockIdx.x * blockDim.x + threadIdx.x;
    if (t >= n * 8) return;
    int i = t >> 3, f2 = t & 7;
    float di = dis[i];
    int beg = offsets[i], end = offsets[i + 1];
    float2 acc = __half22float2(g2[(size_t)i * 8 + f2]);  // self-loop
    for (int e = beg; e < end; ++e) {
        float2 v = __half22float2(g2[(size_t)ssrc[e] * 8 + f2]);
        acc.x += v.x;
        acc.y += v.y;
    }
    int f = f2 * 2;
    float u = fmaxf(di * acc.x + b1[f], 0.f) * W2[f]
            + fmaxf(di * acc.y + b1[f + 1], 0.f) * W2[f + 1];
#pragma unroll
    for (int m = 4; m >= 1; m >>= 1) u += __shfl_xor(u, m, 8);
    if (f2 == 0) tbuf[i] = di * u;
}

// 8 threads/node, lane-strided edges (coalesced ssrc), shuffle reduce:
// out[i] = dis[i] * (sum_e t[src] + t[i]) + b2
__global__ void k_gather2(const int* __restrict__ offsets, const int* __restrict__ ssrc,
                          const float* __restrict__ tbuf, const float* __restrict__ dis,
                          const float* __restrict__ b2, float* __restrict__ out, int n) {
    int t = blockIdx.x * blockDim.x + threadIdx.x;
    if (t >= n * 8) return;
    int i = t >> 3, l = t & 7;
    int beg = offsets[i], end = offsets[i + 1];
    float acc = (l == 0) ? tbuf[i] : 0.f;
    for (int e = beg + l; e < end; e += 8) acc += tbuf[ssrc[e]];
#pragma unroll
    for (int m = 4; m >= 1; m >>= 1) acc += __shfl_xor(acc, m, 8);
    if (l == 0) out[i] = dis[i] * acc + b2[0];
}

extern "C" void kernel_launch(void* const* d_in, const int* in_sizes, int n_in,
                              void* d_out, int out_size, void* d_ws, size_t ws_size,
                              hipStream_t stream) {
    const float* x  = (const float*)d_in[0];
    const int*   ei = (const int*)d_in[1];
    const float* W1 = (const float*)d_in[2];
    const float* b1 = (const float*)d_in[3];
    const float* W2 = (const float*)d_in[4];
    const float* b2 = (const float*)d_in[5];
    float* out = (float*)d_out;

    const int N = in_sizes[0] / 128;   // 100000
    const int E = in_sizes[1] / 2;     // 3200000
    const int* row = ei;        // edge_index[0] = source
    const int* col = ei + E;    // edge_index[1] = target
    const int NB = (N + 255) >> CB;    // coarse buckets (391)

    // workspace (4B units): big[max(E,8N)] (ebuf, later aliased by g fp16) |
    // dis[N] | tbuf[N] | offsets[N+1] | ssrc[E] | cc[512] | coff[513] | gcur[512]
    size_t bigsz = (size_t)E > (size_t)N * 8 ? (size_t)E : (size_t)N * 8;
    int*    ebuf    = (int*)d_ws;
    __half* gh      = (__half*)d_ws;    // aliases ebuf (ebuf dead before gemm1)
    float*  dis     = (float*)d_ws + bigsz;
    float*  tbuf    = dis + N;
    int*    offsets = (int*)(tbuf + N);
    int*    ssrc    = offsets + (N + 1);
    int*    cc      = ssrc + E;
    int*    coff    = cc + 512;
    int*    gcur    = coff + 513;

    auto cdiv = [](int a, int b) { return (a + b - 1) / b; };

    hipMemsetAsync(cc, 0, 512 * sizeof(int), stream);
    k_coarse_count<<<512,              256, 0, stream>>>(col, cc, E, NB);
    k_coarse_scan <<<1,                512, 0, stream>>>(cc, coff, gcur, NB);
    k_partition   <<<cdiv(E, TILE),    256, 0, stream>>>(row, col, gcur, ebuf, E, NB);
    k_bucket      <<<NB,               256, 0, stream>>>(ebuf, coff, offsets, ssrc, dis, N, E);
    k_gemm1       <<<cdiv(N, 256),     256, 0, stream>>>(x, W1, dis, gh, N);
    k_gather1     <<<cdiv(N * 8, 256), 256, 0, stream>>>(offsets, ssrc, (const __half2*)gh,
                                                         dis, b1, W2, tbuf, N);
    k_gather2     <<<cdiv(N * 8, 256), 256, 0, stream>>>(offsets, ssrc, tbuf, dis, b2, out, N);
}

// Round 5
// 253.690 us; speedup vs baseline: 4.3131x; 1.1318x over previous
//
#include <hip/hip_runtime.h>
#include <hip/hip_fp16.h>

// 2-layer GCN via CSR gather built by a two-level counting sort with
// fixed-capacity (padded) coarse buckets:
//   k_init_gcur: gcur[b] = b*CAP  (kills coarse count+scan+memset)
//   k_partition: LDS coarse histogram, reserve runs, re-read & place (no spill)
//   k_bucket:    stage bucket edges in LDS once; fine hist+scan+place -> ssrc,
//                beg/end, dis
//   k_gemm1:     g = fp16(dis * (x@W1))  [3.2MB table, L2-resident]
//   k_gather1:   8 lanes/node half2 gather + relu + dot(W2) -> t
//   k_gather2:   8 lanes/node scalar gather -> out

#define CB 8                  // coarse bucket = col >> CB (256 nodes/bucket)
#define CAP 9216              // max edges per bucket (mean 8192 + 11 sigma)
#define TILE 4096             // edges per partition block (256 thr x 16)

__global__ void k_init_gcur(int* __restrict__ gcur, int nb) {
    int b = blockIdx.x * blockDim.x + threadIdx.x;
    if (b < nb) gcur[b] = b * CAP;
}

// Pack (col&255)<<17 | row  (row < 2^17). Phase A: coarse LDS histogram of col.
// Reserve per-bucket runs. Phase B: re-read col/row (L2-hot) and place.
__global__ void __launch_bounds__(256) k_partition(
        const int* __restrict__ row, const int* __restrict__ col,
        int* __restrict__ gcur, int* __restrict__ ebuf, int e, int nb) {
    __shared__ int hist[512];
    __shared__ int gbase[512];
    const int base = blockIdx.x * TILE;
    for (int t = threadIdx.x; t < nb; t += 256) hist[t] = 0;
    __syncthreads();
#pragma unroll
    for (int k = 0; k < 16; ++k) {
        int i = base + (k << 8) + threadIdx.x;
        if (i < e) atomicAdd(&hist[col[i] >> CB], 1);
    }
    __syncthreads();
    for (int t = threadIdx.x; t < nb; t += 256) {
        int h = hist[t];
        gbase[t] = h ? atomicAdd(&gcur[t], h) : 0;
        hist[t] = 0;  // reuse as local cursor
    }
    __syncthreads();
#pragma unroll
    for (int k = 0; k < 16; ++k) {
        int i = base + (k << 8) + threadIdx.x;
        if (i < e) {
            int c = col[i], r = row[i];
            int b = c >> CB;
            int p = gbase[b] + atomicAdd(&hist[b], 1);
            if (p < (b + 1) * CAP)  // overflow guard (statistically unreachable)
                ebuf[p] = ((c & ((1 << CB) - 1)) << 17) | r;
        }
    }
}

// One block per bucket: stage edges in LDS, fine hist + scan + place.
// Emits beg/end (padded CSR), dis, and sorted ssrc.
__global__ void __launch_bounds__(256) k_bucket(
        const int* __restrict__ ebuf, const int* __restrict__ gcur,
        int* __restrict__ begA, int* __restrict__ endA, int* __restrict__ ssrc,
        float* __restrict__ dis, int n) {
    __shared__ int ev[CAP];
    __shared__ int hist[256];
    __shared__ int sc[256];
    const int b = blockIdx.x, t = threadIdx.x;
    const int base = b * CAP;
    const int cnt = gcur[b] - base;
    for (int j = t; j < cnt; j += 256) ev[j] = ebuf[base + j];
    hist[t] = 0;
    __syncthreads();
    for (int j = t; j < cnt; j += 256) atomicAdd(&hist[ev[j] >> 17], 1);
    __syncthreads();
    int v = hist[t];
    sc[t] = v;
    __syncthreads();
    for (int off = 1; off < 256; off <<= 1) {
        int add = (t >= off) ? sc[t - off] : 0;
        __syncthreads();
        sc[t] += add;
        __syncthreads();
    }
    int excl = sc[t] - v;
    int node = (b << CB) + t;
    if (node < n) {
        begA[node] = base + excl;
        endA[node] = base + excl + v;
        dis[node] = rsqrtf((float)(v + 1));
    }
    hist[t] = excl;  // local cursor
    __syncthreads();
    for (int j = t; j < cnt; j += 256) {
        int val = ev[j];
        int p = atomicAdd(&hist[val >> 17], 1);
        ssrc[base + p] = val & 0x1FFFF;
    }
}

// g[N,16] (fp16) = dis[row] * (x[N,128] @ W1[128,16]); W1 transposed in LDS
__global__ void k_gemm1(const float* __restrict__ x, const float* __restrict__ W1,
                        const float* __restrict__ dis, __half* __restrict__ gh, int n) {
    __shared__ float wt[16 * 128];
    for (int t = threadIdx.x; t < 2048; t += blockDim.x) {
        int j = t >> 7, k = t & 127;
        wt[t] = W1[k * 16 + j];
    }
    __syncthreads();
    int r = blockIdx.x * blockDim.x + threadIdx.x;
    if (r >= n) return;
    const float4* x4 = (const float4*)(x + (size_t)r * 128);
    const float4* w4 = (const float4*)wt;
    float acc[16];
#pragma unroll
    for (int j = 0; j < 16; ++j) acc[j] = 0.f;
    for (int k4 = 0; k4 < 32; ++k4) {
        float4 vv = x4[k4];
#pragma unroll
        for (int j = 0; j < 16; ++j) {
            float4 w = w4[j * 32 + k4];
            acc[j] += vv.x * w.x + vv.y * w.y + vv.z * w.z + vv.w * w.w;
        }
    }
    float d = dis[r];
    __half2 hh[8];
#pragma unroll
    for (int j = 0; j < 8; ++j)
        hh[j] = __floats2half2_rn(d * acc[2 * j], d * acc[2 * j + 1]);
    uint4* o = (uint4*)(gh + (size_t)r * 16);
    const uint4* src = (const uint4*)hh;
    o[0] = src[0];
    o[1] = src[1];
}

// 8 threads/node, half2 reads (32B/edge, L2-resident table); fp32 accumulate;
// fused relu + bias + dot(W2): t[i] = dis[i]*s[i]
__global__ void k_gather1(const int* __restrict__ begA, const int* __restrict__ endA,
                          const int* __restrict__ ssrc,
                          const __half2* __restrict__ g2, const float* __restrict__ dis,
                          const float* __restrict__ b1, const float* __restrict__ W2,
                          float* __restrict__ tbuf, int n) {
    int t = blockIdx.x * blockDim.x + threadIdx.x;
    if (t >= n * 8) return;
    int i = t >> 3, f2 = t & 7;
    float di = dis[i];
    int beg = begA[i], end = endA[i];
    float2 acc = __half22float2(g2[(size_t)i * 8 + f2]);  // self-loop
    for (int e = beg; e < end; ++e) {
        float2 v = __half22float2(g2[(size_t)ssrc[e] * 8 + f2]);
        acc.x += v.x;
        acc.y += v.y;
    }
    int f = f2 * 2;
    float u = fmaxf(di * acc.x + b1[f], 0.f) * W2[f]
            + fmaxf(di * acc.y + b1[f + 1], 0.f) * W2[f + 1];
#pragma unroll
    for (int m = 4; m >= 1; m >>= 1) u += __shfl_xor(u, m, 8);
    if (f2 == 0) tbuf[i] = di * u;
}

// 8 threads/node, lane-strided edges (coalesced ssrc), shuffle reduce:
// out[i] = dis[i] * (sum_e t[src] + t[i]) + b2
__global__ void k_gather2(const int* __restrict__ begA, const int* __restrict__ endA,
                          const int* __restrict__ ssrc,
                          const float* __restrict__ tbuf, const float* __restrict__ dis,
                          const float* __restrict__ b2, float* __restrict__ out, int n) {
    int t = blockIdx.x * blockDim.x + threadIdx.x;
    if (t >= n * 8) return;
    int i = t >> 3, l = t & 7;
    int beg = begA[i], end = endA[i];
    float acc = (l == 0) ? tbuf[i] : 0.f;
    for (int e = beg + l; e < end; e += 8) acc += tbuf[ssrc[e]];
#pragma unroll
    for (int m = 4; m >= 1; m >>= 1) acc += __shfl_xor(acc, m, 8);
    if (l == 0) out[i] = dis[i] * acc + b2[0];
}

extern "C" void kernel_launch(void* const* d_in, const int* in_sizes, int n_in,
                              void* d_out, int out_size, void* d_ws, size_t ws_size,
                              hipStream_t stream) {
    const float* x  = (const float*)d_in[0];
    const int*   ei = (const int*)d_in[1];
    const float* W1 = (const float*)d_in[2];
    const float* b1 = (const float*)d_in[3];
    const float* W2 = (const float*)d_in[4];
    const float* b2 = (const float*)d_in[5];
    float* out = (float*)d_out;

    const int N = in_sizes[0] / 128;   // 100000
    const int E = in_sizes[1] / 2;     // 3200000
    const int* row = ei;        // edge_index[0] = source
    const int* col = ei + E;    // edge_index[1] = target
    const int NB = (N + 255) >> CB;    // coarse buckets (391)
    const size_t PADE = (size_t)NB * CAP;  // padded edge capacity

    // workspace (4B units): ebuf[PADE] (aliased by gh fp16 after k_bucket) |
    // ssrc[PADE] | dis[N] | tbuf[N] | begA[N] | endA[N] | gcur[512]
    size_t bigsz = PADE > (size_t)N * 8 ? PADE : (size_t)N * 8;
    int*    ebuf = (int*)d_ws;
    __half* gh   = (__half*)d_ws;      // aliases ebuf (dead before k_gemm1)
    int*    ssrc = (int*)d_ws + bigsz;
    float*  dis  = (float*)(ssrc + PADE);
    float*  tbuf = dis + N;
    int*    begA = (int*)(tbuf + N);
    int*    endA = begA + N;
    int*    gcur = endA + N;

    auto cdiv = [](int a, int b) { return (a + b - 1) / b; };

    k_init_gcur<<<cdiv(NB, 256),    256, 0, stream>>>(gcur, NB);
    k_partition<<<cdiv(E, TILE),    256, 0, stream>>>(row, col, gcur, ebuf, E, NB);
    k_bucket   <<<NB,               256, 0, stream>>>(ebuf, gcur, begA, endA, ssrc, dis, N);
    k_gemm1    <<<cdiv(N, 256),     256, 0, stream>>>(x, W1, dis, gh, N);
    k_gather1  <<<cdiv(N * 8, 256), 256, 0, stream>>>(begA, endA, ssrc, (const __half2*)gh,
                                                      dis, b1, W2, tbuf, N);
    k_gather2  <<<cdiv(N * 8, 256), 256, 0, stream>>>(begA, endA, ssrc, tbuf, dis, b2, out, N);
}

// Round 6
// 238.856 us; speedup vs baseline: 4.5810x; 1.0621x over previous
//
#include <hip/hip_runtime.h>
#include <hip/hip_fp16.h>

// 2-layer GCN via CSR gather built by a two-level counting sort with
// fixed-capacity (padded) coarse buckets:
//   k_init_gcur: gcur[b] = b*CAP
//   k_partition: LDS coarse hist -> scan -> rank tile into LDS-sorted order ->
//                linear coalesced emit (no per-element atomics on the emit)
//   k_bucket:    fine hist+scan in 2KB LDS, ebuf re-read from L2 -> ssrc/beg/end/dis
//   k_gemm1:     g = fp16(dis * (x@W1))  [3.2MB table, L2-resident]
//   k_gather1:   8 lanes/node half2 gather + relu + dot(W2) -> t
//   k_gather2:   8 lanes/node scalar gather -> out

#define CB 8                  // coarse bucket = col >> CB (256 nodes/bucket)
#define CAP 9216              // max edges per bucket (mean 8192 + 11 sigma)
#define TILE 4096             // edges per partition block (512 thr x 8)

__global__ void k_init_gcur(int* __restrict__ gcur, int nb) {
    int b = blockIdx.x * blockDim.x + threadIdx.x;
    if (b < nb) gcur[b] = b * CAP;
}

// Pack (col&255)<<17 | row  (row < 2^17).
__global__ void __launch_bounds__(512) k_partition(
        const int* __restrict__ row, const int* __restrict__ col,
        int* __restrict__ gcur, int* __restrict__ ebuf, int e, int nb) {
    __shared__ int hist[512];            // counts -> local cursor
    __shared__ int lbase[512];           // exclusive scan (local base)
    __shared__ int gdelta[512];          // gbase[b] - lbase[b]
    __shared__ int sval[TILE];           // tile sorted by bucket
    __shared__ unsigned short sbkt[TILE];
    const int base = blockIdx.x * TILE;
    const int cnt = min(TILE, e - base);
    const int t = threadIdx.x;
    hist[t] = 0;
    __syncthreads();
#pragma unroll
    for (int k = 0; k < TILE / 512; ++k) {
        int i = base + (k << 9) + t;
        if (i < e) atomicAdd(&hist[col[i] >> CB], 1);
    }
    __syncthreads();
    int v = hist[t];
    lbase[t] = v;
    __syncthreads();
    for (int off = 1; off < 512; off <<= 1) {
        int add = (t >= off) ? lbase[t - off] : 0;
        __syncthreads();
        lbase[t] += add;
        __syncthreads();
    }
    int excl = lbase[t] - v;
    __syncthreads();
    lbase[t] = excl;
    int gb = v ? atomicAdd(&gcur[t], v) : 0;   // t >= nb has v == 0
    gdelta[t] = gb - excl;
    hist[t] = excl;                            // local rank cursor
    __syncthreads();
#pragma unroll
    for (int k = 0; k < TILE / 512; ++k) {
        int i = base + (k << 9) + t;
        if (i < e) {
            int c = col[i], r = row[i];
            int b = c >> CB;
            int p = atomicAdd(&hist[b], 1);
            sval[p] = ((c & ((1 << CB) - 1)) << 17) | r;
            sbkt[p] = (unsigned short)b;
        }
    }
    __syncthreads();
    for (int j = t; j < cnt; j += 512) {       // coalesced emit
        int b = sbkt[j];
        int p = gdelta[b] + j;                 // == gbase[b] + (j - lbase[b])
        if (p < (b + 1) * CAP) ebuf[p] = sval[j];  // overflow guard
    }
}

// One block per bucket: fine hist + scan (2KB LDS), ebuf re-read from L2.
__global__ void __launch_bounds__(256) k_bucket(
        const int* __restrict__ ebuf, const int* __restrict__ gcur,
        int* __restrict__ begA, int* __restrict__ endA, int* __restrict__ ssrc,
        float* __restrict__ dis, int n) {
    __shared__ int hist[256];
    __shared__ int sc[256];
    const int b = blockIdx.x, t = threadIdx.x;
    const int base = b * CAP;
    const int cnt = min(gcur[b] - base, CAP);
    hist[t] = 0;
    __syncthreads();
    for (int j = t; j < cnt; j += 256) atomicAdd(&hist[ebuf[base + j] >> 17], 1);
    __syncthreads();
    int v = hist[t];
    sc[t] = v;
    __syncthreads();
    for (int off = 1; off < 256; off <<= 1) {
        int add = (t >= off) ? sc[t - off] : 0;
        __syncthreads();
        sc[t] += add;
        __syncthreads();
    }
    int excl = sc[t] - v;
    int node = (b << CB) + t;
    if (node < n) {
        begA[node] = base + excl;
        endA[node] = base + excl + v;
        dis[node] = rsqrtf((float)(v + 1));
    }
    hist[t] = excl;  // local cursor
    __syncthreads();
    for (int j = t; j < cnt; j += 256) {
        int val = ebuf[base + j];
        int p = atomicAdd(&hist[val >> 17], 1);
        ssrc[base + p] = val & 0x1FFFF;
    }
}

// g[N,16] (fp16) = dis[row] * (x[N,128] @ W1[128,16]); W1 transposed in LDS
__global__ void k_gemm1(const float* __restrict__ x, const float* __restrict__ W1,
                        const float* __restrict__ dis, __half* __restrict__ gh, int n) {
    __shared__ float wt[16 * 128];
    for (int t = threadIdx.x; t < 2048; t += blockDim.x) {
        int j = t >> 7, k = t & 127;
        wt[t] = W1[k * 16 + j];
    }
    __syncthreads();
    int r = blockIdx.x * blockDim.x + threadIdx.x;
    if (r >= n) return;
    const float4* x4 = (const float4*)(x + (size_t)r * 128);
    const float4* w4 = (const float4*)wt;
    float acc[16];
#pragma unroll
    for (int j = 0; j < 16; ++j) acc[j] = 0.f;
    for (int k4 = 0; k4 < 32; ++k4) {
        float4 vv = x4[k4];
#pragma unroll
        for (int j = 0; j < 16; ++j) {
            float4 w = w4[j * 32 + k4];
            acc[j] += vv.x * w.x + vv.y * w.y + vv.z * w.z + vv.w * w.w;
        }
    }
    float d = dis[r];
    __half2 hh[8];
#pragma unroll
    for (int j = 0; j < 8; ++j)
        hh[j] = __floats2half2_rn(d * acc[2 * j], d * acc[2 * j + 1]);
    uint4* o = (uint4*)(gh + (size_t)r * 16);
    const uint4* src = (const uint4*)hh;
    o[0] = src[0];
    o[1] = src[1];
}

// 8 threads/node, half2 reads (32B/edge, L2-resident table); fp32 accumulate;
// fused relu + bias + dot(W2): t[i] = dis[i]*s[i]
__global__ void k_gather1(const int* __restrict__ begA, const int* __restrict__ endA,
                          const int* __restrict__ ssrc,
                          const __half2* __restrict__ g2, const float* __restrict__ dis,
                          const float* __restrict__ b1, const float* __restrict__ W2,
                          float* __restrict__ tbuf, int n) {
    int t = blockIdx.x * blockDim.x + threadIdx.x;
    if (t >= n * 8) return;
    int i = t >> 3, f2 = t & 7;
    float di = dis[i];
    int beg = begA[i], end = endA[i];
    float2 acc = __half22float2(g2[(size_t)i * 8 + f2]);  // self-loop
    for (int e = beg; e < end; ++e) {
        float2 v = __half22float2(g2[(size_t)ssrc[e] * 8 + f2]);
        acc.x += v.x;
        acc.y += v.y;
    }
    int f = f2 * 2;
    float u = fmaxf(di * acc.x + b1[f], 0.f) * W2[f]
            + fmaxf(di * acc.y + b1[f + 1], 0.f) * W2[f + 1];
#pragma unroll
    for (int m = 4; m >= 1; m >>= 1) u += __shfl_xor(u, m, 8);
    if (f2 == 0) tbuf[i] = di * u;
}

// 8 threads/node, lane-strided edges (coalesced ssrc), shuffle reduce:
// out[i] = dis[i] * (sum_e t[src] + t[i]) + b2
__global__ void k_gather2(const int* __restrict__ begA, const int* __restrict__ endA,
                          const int* __restrict__ ssrc,
                          const float* __restrict__ tbuf, const float* __restrict__ dis,
                          const float* __restrict__ b2, float* __restrict__ out, int n) {
    int t = blockIdx.x * blockDim.x + threadIdx.x;
    if (t >= n * 8) return;
    int i = t >> 3, l = t & 7;
    int beg = begA[i], end = endA[i];
    float acc = (l == 0) ? tbuf[i] : 0.f;
    for (int e = beg + l; e < end; e += 8) acc += tbuf[ssrc[e]];
#pragma unroll
    for (int m = 4; m >= 1; m >>= 1) acc += __shfl_xor(acc, m, 8);
    if (l == 0) out[i] = dis[i] * acc + b2[0];
}

extern "C" void kernel_launch(void* const* d_in, const int* in_sizes, int n_in,
                              void* d_out, int out_size, void* d_ws, size_t ws_size,
                              hipStream_t stream) {
    const float* x  = (const float*)d_in[0];
    const int*   ei = (const int*)d_in[1];
    const float* W1 = (const float*)d_in[2];
    const float* b1 = (const float*)d_in[3];
    const float* W2 = (const float*)d_in[4];
    const float* b2 = (const float*)d_in[5];
    float* out = (float*)d_out;

    const int N = in_sizes[0] / 128;   // 100000
    const int E = in_sizes[1] / 2;     // 3200000
    const int* row = ei;        // edge_index[0] = source
    const int* col = ei + E;    // edge_index[1] = target
    const int NB = (N + 255) >> CB;    // coarse buckets (391)
    const size_t PADE = (size_t)NB * CAP;  // padded edge capacity

    // workspace (4B units): ebuf[PADE] (aliased by gh fp16 after k_bucket) |
    // ssrc[PADE] | dis[N] | tbuf[N] | begA[N] | endA[N] | gcur[512]
    size_t bigsz = PADE > (size_t)N * 8 ? PADE : (size_t)N * 8;
    int*    ebuf = (int*)d_ws;
    __half* gh   = (__half*)d_ws;      // aliases ebuf (dead before k_gemm1)
    int*    ssrc = (int*)d_ws + bigsz;
    float*  dis  = (float*)(ssrc + PADE);
    float*  tbuf = dis + N;
    int*    begA = (int*)(tbuf + N);
    int*    endA = begA + N;
    int*    gcur = endA + N;

    auto cdiv = [](int a, int b) { return (a + b - 1) / b; };

    k_init_gcur<<<cdiv(NB, 256),    256, 0, stream>>>(gcur, NB);
    k_partition<<<cdiv(E, TILE),    512, 0, stream>>>(row, col, gcur, ebuf, E, NB);
    k_bucket   <<<NB,               256, 0, stream>>>(ebuf, gcur, begA, endA, ssrc, dis, N);
    k_gemm1    <<<cdiv(N, 256),     256, 0, stream>>>(x, W1, dis, gh, N);
    k_gather1  <<<cdiv(N * 8, 256), 256, 0, stream>>>(begA, endA, ssrc, (const __half2*)gh,
                                                      dis, b1, W2, tbuf, N);
    k_gather2  <<<cdiv(N * 8, 256), 256, 0, stream>>>(begA, endA, ssrc, tbuf, dis, b2, out, N);
}

// Round 7
// 217.668 us; speedup vs baseline: 5.0269x; 1.0973x over previous
//
#include <hip/hip_runtime.h>
#include <hip/hip_fp16.h>

// 2-layer GCN via CSR gather built by a two-level counting sort with
// fixed-capacity (padded) coarse buckets:
//   k_init_gcur: gcur[b] = b*CAP
//   k_partition: LDS coarse hist -> scan -> rank tile into LDS-sorted order ->
//                linear coalesced emit (no per-element atomics on the emit)
//   k_bucket:    fine hist+scan in 2KB LDS, ebuf re-read from L2 -> ssrc/beg/end/dis
//   k_gemm1:     g = fp16(dis * (x@W1))  [3.2MB table, L2-resident]
//   k_gather1:   8 lanes/node half2 gather (unroll x8 for MLP) + relu + dot(W2) -> t
//   k_gather2:   8 lanes/node scalar gather (unroll x4) -> out

#define CB 8                  // coarse bucket = col >> CB (256 nodes/bucket)
#define CAP 9216              // max edges per bucket (mean 8192 + 11 sigma)
#define TILE 4096             // edges per partition block (512 thr x 8)

__global__ void k_init_gcur(int* __restrict__ gcur, int nb) {
    int b = blockIdx.x * blockDim.x + threadIdx.x;
    if (b < nb) gcur[b] = b * CAP;
}

// Pack (col&255)<<17 | row  (row < 2^17).
__global__ void __launch_bounds__(512) k_partition(
        const int* __restrict__ row, const int* __restrict__ col,
        int* __restrict__ gcur, int* __restrict__ ebuf, int e, int nb) {
    __shared__ int hist[512];            // counts -> local cursor
    __shared__ int lbase[512];           // exclusive scan (local base)
    __shared__ int gdelta[512];          // gbase[b] - lbase[b]
    __shared__ int sval[TILE];           // tile sorted by bucket
    __shared__ unsigned short sbkt[TILE];
    const int base = blockIdx.x * TILE;
    const int cnt = min(TILE, e - base);
    const int t = threadIdx.x;
    hist[t] = 0;
    __syncthreads();
#pragma unroll
    for (int k = 0; k < TILE / 512; ++k) {
        int i = base + (k << 9) + t;
        if (i < e) atomicAdd(&hist[col[i] >> CB], 1);
    }
    __syncthreads();
    int v = hist[t];
    lbase[t] = v;
    __syncthreads();
    for (int off = 1; off < 512; off <<= 1) {
        int add = (t >= off) ? lbase[t - off] : 0;
        __syncthreads();
        lbase[t] += add;
        __syncthreads();
    }
    int excl = lbase[t] - v;
    __syncthreads();
    lbase[t] = excl;
    int gb = v ? atomicAdd(&gcur[t], v) : 0;   // t >= nb has v == 0
    gdelta[t] = gb - excl;
    hist[t] = excl;                            // local rank cursor
    __syncthreads();
#pragma unroll
    for (int k = 0; k < TILE / 512; ++k) {
        int i = base + (k << 9) + t;
        if (i < e) {
            int c = col[i], r = row[i];
            int b = c >> CB;
            int p = atomicAdd(&hist[b], 1);
            sval[p] = ((c & ((1 << CB) - 1)) << 17) | r;
            sbkt[p] = (unsigned short)b;
        }
    }
    __syncthreads();
    for (int j = t; j < cnt; j += 512) {       // coalesced emit
        int b = sbkt[j];
        int p = gdelta[b] + j;                 // == gbase[b] + (j - lbase[b])
        if (p < (b + 1) * CAP) ebuf[p] = sval[j];  // overflow guard
    }
}

// One block per bucket: fine hist + scan (2KB LDS), ebuf re-read from L2.
__global__ void __launch_bounds__(256) k_bucket(
        const int* __restrict__ ebuf, const int* __restrict__ gcur,
        int* __restrict__ begA, int* __restrict__ endA, int* __restrict__ ssrc,
        float* __restrict__ dis, int n) {
    __shared__ int hist[256];
    __shared__ int sc[256];
    const int b = blockIdx.x, t = threadIdx.x;
    const int base = b * CAP;
    const int cnt = min(gcur[b] - base, CAP);
    hist[t] = 0;
    __syncthreads();
    for (int j = t; j < cnt; j += 256) atomicAdd(&hist[ebuf[base + j] >> 17], 1);
    __syncthreads();
    int v = hist[t];
    sc[t] = v;
    __syncthreads();
    for (int off = 1; off < 256; off <<= 1) {
        int add = (t >= off) ? sc[t - off] : 0;
        __syncthreads();
        sc[t] += add;
        __syncthreads();
    }
    int excl = sc[t] - v;
    int node = (b << CB) + t;
    if (node < n) {
        begA[node] = base + excl;
        endA[node] = base + excl + v;
        dis[node] = rsqrtf((float)(v + 1));
    }
    hist[t] = excl;  // local cursor
    __syncthreads();
    for (int j = t; j < cnt; j += 256) {
        int val = ebuf[base + j];
        int p = atomicAdd(&hist[val >> 17], 1);
        ssrc[base + p] = val & 0x1FFFF;
    }
}

// g[N,16] (fp16) = dis[row] * (x[N,128] @ W1[128,16]); W1 transposed in LDS
__global__ void k_gemm1(const float* __restrict__ x, const float* __restrict__ W1,
                        const float* __restrict__ dis, __half* __restrict__ gh, int n) {
    __shared__ float wt[16 * 128];
    for (int t = threadIdx.x; t < 2048; t += blockDim.x) {
        int j = t >> 7, k = t & 127;
        wt[t] = W1[k * 16 + j];
    }
    __syncthreads();
    int r = blockIdx.x * blockDim.x + threadIdx.x;
    if (r >= n) return;
    const float4* x4 = (const float4*)(x + (size_t)r * 128);
    const float4* w4 = (const float4*)wt;
    float acc[16];
#pragma unroll
    for (int j = 0; j < 16; ++j) acc[j] = 0.f;
    for (int k4 = 0; k4 < 32; ++k4) {
        float4 vv = x4[k4];
#pragma unroll
        for (int j = 0; j < 16; ++j) {
            float4 w = w4[j * 32 + k4];
            acc[j] += vv.x * w.x + vv.y * w.y + vv.z * w.z + vv.w * w.w;
        }
    }
    float d = dis[r];
    __half2 hh[8];
#pragma unroll
    for (int j = 0; j < 8; ++j)
        hh[j] = __floats2half2_rn(d * acc[2 * j], d * acc[2 * j + 1]);
    uint4* o = (uint4*)(gh + (size_t)r * 16);
    const uint4* src = (const uint4*)hh;
    o[0] = src[0];
    o[1] = src[1];
}

// 8 threads/node, half2 reads (32B/edge, L2-resident table); fp32 accumulate;
// edge loop unrolled x8 so 8 random loads are in flight per thread.
// fused relu + bias + dot(W2): t[i] = dis[i]*s[i]
__global__ void k_gather1(const int* __restrict__ begA, const int* __restrict__ endA,
                          const int* __restrict__ ssrc,
                          const __half2* __restrict__ g2, const float* __restrict__ dis,
                          const float* __restrict__ b1, const float* __restrict__ W2,
                          float* __restrict__ tbuf, int n) {
    int t = blockIdx.x * blockDim.x + threadIdx.x;
    if (t >= n * 8) return;
    int i = t >> 3, f2 = t & 7;
    float di = dis[i];
    int beg = begA[i], end = endA[i];
    float2 acc = __half22float2(g2[(size_t)i * 8 + f2]);  // self-loop
    float2 acc1 = make_float2(0.f, 0.f);
    int e = beg;
    for (; e + 8 <= end; e += 8) {
        int s0 = ssrc[e + 0], s1 = ssrc[e + 1], s2 = ssrc[e + 2], s3 = ssrc[e + 3];
        int s4 = ssrc[e + 4], s5 = ssrc[e + 5], s6 = ssrc[e + 6], s7 = ssrc[e + 7];
        float2 v0 = __half22float2(g2[(size_t)s0 * 8 + f2]);
        float2 v1 = __half22float2(g2[(size_t)s1 * 8 + f2]);
        float2 v2 = __half22float2(g2[(size_t)s2 * 8 + f2]);
        float2 v3 = __half22float2(g2[(size_t)s3 * 8 + f2]);
        float2 v4 = __half22float2(g2[(size_t)s4 * 8 + f2]);
        float2 v5 = __half22float2(g2[(size_t)s5 * 8 + f2]);
        float2 v6 = __half22float2(g2[(size_t)s6 * 8 + f2]);
        float2 v7 = __half22float2(g2[(size_t)s7 * 8 + f2]);
        acc.x  += v0.x; acc.y  += v0.y;  acc1.x += v1.x; acc1.y += v1.y;
        acc.x  += v2.x; acc.y  += v2.y;  acc1.x += v3.x; acc1.y += v3.y;
        acc.x  += v4.x; acc.y  += v4.y;  acc1.x += v5.x; acc1.y += v5.y;
        acc.x  += v6.x; acc.y  += v6.y;  acc1.x += v7.x; acc1.y += v7.y;
    }
    for (; e < end; ++e) {
        float2 v = __half22float2(g2[(size_t)ssrc[e] * 8 + f2]);
        acc.x += v.x; acc.y += v.y;
    }
    acc.x += acc1.x; acc.y += acc1.y;
    int f = f2 * 2;
    float u = fmaxf(di * acc.x + b1[f], 0.f) * W2[f]
            + fmaxf(di * acc.y + b1[f + 1], 0.f) * W2[f + 1];
#pragma unroll
    for (int m = 4; m >= 1; m >>= 1) u += __shfl_xor(u, m, 8);
    if (f2 == 0) tbuf[i] = di * u;
}

// 8 threads/node, lane-strided edges (coalesced ssrc), unroll x4 for MLP:
// out[i] = dis[i] * (sum_e t[src] + t[i]) + b2
__global__ void k_gather2(const int* __restrict__ begA, const int* __restrict__ endA,
                          const int* __restrict__ ssrc,
                          const float* __restrict__ tbuf, const float* __restrict__ dis,
                          const float* __restrict__ b2, float* __restrict__ out, int n) {
    int t = blockIdx.x * blockDim.x + threadIdx.x;
    if (t >= n * 8) return;
    int i = t >> 3, l = t & 7;
    int beg = begA[i], end = endA[i];
    float acc = (l == 0) ? tbuf[i] : 0.f;
    float acc1 = 0.f;
    int e = beg + l;
    for (; e + 24 < end; e += 32) {
        int s0 = ssrc[e], s1 = ssrc[e + 8], s2 = ssrc[e + 16], s3 = ssrc[e + 24];
        float v0 = tbuf[s0], v1 = tbuf[s1], v2 = tbuf[s2], v3 = tbuf[s3];
        acc += v0; acc1 += v1; acc += v2; acc1 += v3;
    }
    for (; e < end; e += 8) acc += tbuf[ssrc[e]];
    acc += acc1;
#pragma unroll
    for (int m = 4; m >= 1; m >>= 1) acc += __shfl_xor(acc, m, 8);
    if (l == 0) out[i] = dis[i] * acc + b2[0];
}

extern "C" void kernel_launch(void* const* d_in, const int* in_sizes, int n_in,
                              void* d_out, int out_size, void* d_ws, size_t ws_size,
                              hipStream_t stream) {
    const float* x  = (const float*)d_in[0];
    const int*   ei = (const int*)d_in[1];
    const float* W1 = (const float*)d_in[2];
    const float* b1 = (const float*)d_in[3];
    const float* W2 = (const float*)d_in[4];
    const float* b2 = (const float*)d_in[5];
    float* out = (float*)d_out;

    const int N = in_sizes[0] / 128;   // 100000
    const int E = in_sizes[1] / 2;     // 3200000
    const int* row = ei;        // edge_index[0] = source
    const int* col = ei + E;    // edge_index[1] = target
    const int NB = (N + 255) >> CB;    // coarse buckets (391)
    const size_t PADE = (size_t)NB * CAP;  // padded edge capacity

    // workspace (4B units): ebuf[PADE] (aliased by gh fp16 after k_bucket) |
    // ssrc[PADE] | dis[N] | tbuf[N] | begA[N] | endA[N] | gcur[512]
    size_t bigsz = PADE > (size_t)N * 8 ? PADE : (size_t)N * 8;
    int*    ebuf = (int*)d_ws;
    __half* gh   = (__half*)d_ws;      // aliases ebuf (dead before k_gemm1)
    int*    ssrc = (int*)d_ws + bigsz;
    float*  dis  = (float*)(ssrc + PADE);
    float*  tbuf = dis + N;
    int*    begA = (int*)(tbuf + N);
    int*    endA = begA + N;
    int*    gcur = endA + N;

    auto cdiv = [](int a, int b) { return (a + b - 1) / b; };

    k_init_gcur<<<cdiv(NB, 256),    256, 0, stream>>>(gcur, NB);
    k_partition<<<cdiv(E, TILE),    512, 0, stream>>>(row, col, gcur, ebuf, E, NB);
    k_bucket   <<<NB,               256, 0, stream>>>(ebuf, gcur, begA, endA, ssrc, dis, N);
    k_gemm1    <<<cdiv(N, 256),     256, 0, stream>>>(x, W1, dis, gh, N);
    k_gather1  <<<cdiv(N * 8, 256), 256, 0, stream>>>(begA, endA, ssrc, (const __half2*)gh,
                                                      dis, b1, W2, tbuf, N);
    k_gather2  <<<cdiv(N * 8, 256), 256, 0, stream>>>(begA, endA, ssrc, tbuf, dis, b2, out, N);
}